// Round 2
// baseline (196.718 us; speedup 1.0000x reference)
//
#include <hip/hip_runtime.h>

// RecursiveNN root = sum of leaf embeddings: out[b,d] = sum_l emb[ids[b,l], d]
// B=4096 trees, L=64 leaves, D=300, VOCAB=100000, fp32.
//
// Design (R1): one wave per tree, 4 trees per 256-thread block, no LDS.
//  - lane l holds leaf id l in a register; readlane broadcasts each row id
//    (scalar base address -> SGPR addressing, minimal VALU).
//  - main loop: 64 coalesced 1024B row loads (lanes 0..63, float4 each).
//  - tail loop: cols 256..299 (176B/row), exec-masked once (lanes 0..10).
//  - accumulate entirely in registers; write 1200B per tree, coalesced.

#define NB 4096
#define NL 64
#define ND 300
#define ND4 75   // float4 per row

__global__ __launch_bounds__(256, 8) void recnn_root_sum(
    const int* __restrict__ word_ids,     // [NB, NL]
    const float4* __restrict__ emb4,      // [VOCAB, ND4]
    float4* __restrict__ out4)            // [NB, ND4]
{
    const int tid  = threadIdx.x;
    const int wave = tid >> 6;
    const int lane = tid & 63;
    const int tree = blockIdx.x * 4 + wave;

    // Each lane holds one leaf id (coalesced 256B load per wave).
    const int myid = word_ids[tree * NL + lane];

    float4 acc0 = make_float4(0.f, 0.f, 0.f, 0.f);

    // Main: cols 0..255 of every row.
    #pragma unroll 8
    for (int i = 0; i < NL; ++i) {
        const int row = __builtin_amdgcn_readlane(myid, i);
        const float4 v = emb4[(size_t)row * ND4 + lane];
        acc0.x += v.x; acc0.y += v.y; acc0.z += v.z; acc0.w += v.w;
    }

    float4* op = out4 + (size_t)tree * ND4;
    op[lane] = acc0;

    // Tail: cols 256..299 (11 float4), lanes 0..10 only — one exec-mask set.
    if (lane < ND4 - 64) {
        float4 acc1 = make_float4(0.f, 0.f, 0.f, 0.f);
        #pragma unroll 8
        for (int i = 0; i < NL; ++i) {
            const int row = __builtin_amdgcn_readlane(myid, i);
            const float4 v = emb4[(size_t)row * ND4 + 64 + lane];
            acc1.x += v.x; acc1.y += v.y; acc1.z += v.z; acc1.w += v.w;
        }
        op[64 + lane] = acc1;
    }
}

extern "C" void kernel_launch(void* const* d_in, const int* in_sizes, int n_in,
                              void* d_out, int out_size, void* d_ws, size_t ws_size,
                              hipStream_t stream) {
    const int*    word_ids = (const int*)d_in[0];      // [4096, 64] int32
    const float4* emb4     = (const float4*)d_in[1];   // [100000, 75] float4
    float4*       out4     = (float4*)d_out;           // [4096, 75] float4

    recnn_root_sum<<<NB / 4, 256, 0, stream>>>(word_ids, emb4, out4);
}

// Round 4
// 195.196 us; speedup vs baseline: 1.0078x; 1.0078x over previous
//
#include <hip/hip_runtime.h>

// RecursiveNN root = sum of leaf embeddings: out[b,d] = sum_l emb[ids[b,l], d]
// B=4096 trees, L=64 leaves, D=300, VOCAB=100000, fp32.
//
// R3 = R2 resubmitted (container infra failure, no data collected).
// Design: 2 waves per tree (32 rows each) -> 8192 waves = 32 waves/CU
// (double R1's 16) to test latency- vs BW-bound. Block = 256 thr = 4 waves
// = 2 trees. Cheap LDS cross-wave reduce (one sync).

#define NB 4096
#define NL 64
#define ND 300
#define ND4 75   // float4 per row

__global__ __launch_bounds__(256, 8) void recnn_root_sum(
    const int* __restrict__ word_ids,     // [NB, NL]
    const float4* __restrict__ emb4,      // [VOCAB, ND4]
    float* __restrict__ out)              // [NB, ND]
{
    __shared__ float partial[4][ND];

    const int tid  = threadIdx.x;
    const int wave = tid >> 6;
    const int lane = tid & 63;

    const int tree_local = wave >> 1;          // 0..1
    const int half       = wave & 1;           // 0..1 (which 32 rows)
    const int tree       = blockIdx.x * 2 + tree_local;

    // lanes 0..31 hold this wave's 32 leaf ids (lanes 32..63 duplicate).
    const int myid = word_ids[tree * NL + half * 32 + (lane & 31)];

    float4 acc0 = make_float4(0.f, 0.f, 0.f, 0.f);

    // Main: cols 0..255 of this wave's 32 rows.
    #pragma unroll 8
    for (int i = 0; i < 32; ++i) {
        const int row = __builtin_amdgcn_readlane(myid, i);
        const float4 v = emb4[(size_t)row * ND4 + lane];
        acc0.x += v.x; acc0.y += v.y; acc0.z += v.z; acc0.w += v.w;
    }
    *reinterpret_cast<float4*>(&partial[wave][lane * 4]) = acc0;

    // Tail: cols 256..299 (11 float4), lanes 0..10.
    if (lane < ND4 - 64) {
        float4 acc1 = make_float4(0.f, 0.f, 0.f, 0.f);
        #pragma unroll 8
        for (int i = 0; i < 32; ++i) {
            const int row = __builtin_amdgcn_readlane(myid, i);
            const float4 v = emb4[(size_t)row * ND4 + 64 + lane];
            acc1.x += v.x; acc1.y += v.y; acc1.z += v.z; acc1.w += v.w;
        }
        *reinterpret_cast<float4*>(&partial[wave][256 + lane * 4]) = acc1;
    }
    __syncthreads();

    // Cross-wave reduce: tree t sums partial[2t] + partial[2t+1]. 600 outputs.
    for (int t = tid; t < 2 * ND; t += 256) {
        const int tl = t / ND;
        const int c  = t - tl * ND;
        out[(size_t)(blockIdx.x * 2 + tl) * ND + c] =
            partial[2 * tl][c] + partial[2 * tl + 1][c];
    }
}

extern "C" void kernel_launch(void* const* d_in, const int* in_sizes, int n_in,
                              void* d_out, int out_size, void* d_ws, size_t ws_size,
                              hipStream_t stream) {
    const int*    word_ids = (const int*)d_in[0];      // [4096, 64] int32
    const float4* emb4     = (const float4*)d_in[1];   // [100000, 75] float4
    float*        out      = (float*)d_out;            // [4096, 300] f32

    recnn_root_sum<<<NB / 2, 256, 0, stream>>>(word_ids, emb4, out);
}